// Round 1
// baseline (342.573 us; speedup 1.0000x reference)
//
#include <hip/hip_runtime.h>

#define S_LEN 2048
#define HEAD_D 64
#define QBLK 64
#define KVBLK 64

typedef float f32x4 __attribute__((ext_vector_type(4)));
typedef __bf16 bf16x8 __attribute__((ext_vector_type(8)));

__device__ __forceinline__ unsigned short f2bf(float x) {
  __bf16 h = (__bf16)x;
  return __builtin_bit_cast(unsigned short, h);
}

// Flash-attention forward, bf16 MFMA compute, fp32 I/O.
// Block: 256 threads = 4 waves. Each block: 64 q-rows (16/wave). KV tiles of 64.
__global__ __launch_bounds__(256) void flash_attn_fwd(
    const float* __restrict__ Q, const float* __restrict__ K,
    const float* __restrict__ V, float* __restrict__ O)
{
  // K tile [kv][d] bf16, XOR-swizzled rows (elem col ^= (row&7)<<3)
  __shared__ unsigned short kT[64 * 64];
  // V^T tile [d][kv] bf16, same swizzle on rows (row index = d)
  __shared__ unsigned short vT[64 * 64];
  // P staging, wave-private [16][64] each, same swizzle
  __shared__ unsigned short pT[4 * 16 * 64];

  const int tid  = threadIdx.x;
  const int wave = tid >> 6;
  const int lane = tid & 63;
  const int l15  = lane & 15;
  const int l4   = lane >> 4;

  const int qtile = blockIdx.x;
  const int bh    = blockIdx.y;
  const size_t head_off = (size_t)bh * (S_LEN * HEAD_D);
  const float* Qh = Q + head_off;
  const float* Kh = K + head_off;
  const float* Vh = V + head_off;
  float*       Oh = O + head_off;

  // ---- Q fragments (A-frag: row = lane&15, k = (lane>>4)*8 + j), scale folded ----
  bf16x8 qf[2];
  {
    const int qrow = qtile * QBLK + wave * 16 + l15;
    const float* qp = Qh + (size_t)qrow * HEAD_D + l4 * 8;
#pragma unroll
    for (int kk = 0; kk < 2; ++kk) {
      float4 a = *(const float4*)(qp + kk * 32);
      float4 b = *(const float4*)(qp + kk * 32 + 4);
      qf[kk][0] = (__bf16)(a.x * 0.125f);
      qf[kk][1] = (__bf16)(a.y * 0.125f);
      qf[kk][2] = (__bf16)(a.z * 0.125f);
      qf[kk][3] = (__bf16)(a.w * 0.125f);
      qf[kk][4] = (__bf16)(b.x * 0.125f);
      qf[kk][5] = (__bf16)(b.y * 0.125f);
      qf[kk][6] = (__bf16)(b.z * 0.125f);
      qf[kk][7] = (__bf16)(b.w * 0.125f);
    }
  }

  f32x4 o_acc[4];
#pragma unroll
  for (int db = 0; db < 4; ++db) {
#pragma unroll
    for (int r = 0; r < 4; ++r) o_acc[db][r] = 0.0f;
  }
  float m_r[4], l_r[4];
#pragma unroll
  for (int r = 0; r < 4; ++r) { m_r[r] = -1e30f; l_r[r] = 0.0f; }

  unsigned short* pw = pT + wave * (16 * 64);

  for (int kt = 0; kt < S_LEN / KVBLK; ++kt) {
    __syncthreads();  // prior iteration's LDS reads done before overwrite

    // ---- stage K tile (row-major, swizzled) and V^T tile (swizzled) ----
    {
      const float* kg = Kh + (size_t)kt * KVBLK * HEAD_D;
      const float* vg = Vh + (size_t)kt * KVBLK * HEAD_D;
#pragma unroll
      for (int i = 0; i < 4; ++i) {
        const int e   = tid * 4 + i * 1024;  // element index in 64x64 tile
        const int row = e >> 6;
        const int col = e & 63;
        float4 k4 = *(const float4*)(kg + e);
        ushort4 kb;
        kb.x = f2bf(k4.x); kb.y = f2bf(k4.y);
        kb.z = f2bf(k4.z); kb.w = f2bf(k4.w);
        *(ushort4*)&kT[row * 64 + (col ^ ((row & 7) << 3))] = kb;
        float4 v4 = *(const float4*)(vg + e);
        vT[(col + 0) * 64 + (row ^ (((col + 0) & 7) << 3))] = f2bf(v4.x);
        vT[(col + 1) * 64 + (row ^ (((col + 1) & 7) << 3))] = f2bf(v4.y);
        vT[(col + 2) * 64 + (row ^ (((col + 2) & 7) << 3))] = f2bf(v4.z);
        vT[(col + 3) * 64 + (row ^ (((col + 3) & 7) << 3))] = f2bf(v4.w);
      }
    }
    __syncthreads();

    // ---- S = Q K^T : C/D layout row m=(l>>4)*4+r (q), col n=l&15 (kv within n-block) ----
    f32x4 sc[4];
#pragma unroll
    for (int f = 0; f < 4; ++f) {
#pragma unroll
      for (int r = 0; r < 4; ++r) sc[f][r] = 0.0f;
    }
#pragma unroll
    for (int kk = 0; kk < 2; ++kk) {
#pragma unroll
      for (int f = 0; f < 4; ++f) {
        const int row  = f * 16 + l15;                       // kv index (B-frag n = l&15)
        const int colb = (kk * 32 + l4 * 8) ^ ((row & 7) << 3);
        bf16x8 kf = *(const bf16x8*)&kT[row * 64 + colb];
        sc[f] = __builtin_amdgcn_mfma_f32_16x16x32_bf16(qf[kk], kf, sc[f], 0, 0, 0);
      }
    }

    // ---- online softmax (rows spread over 16-lane groups; reduce via shfl_xor) ----
#pragma unroll
    for (int r = 0; r < 4; ++r) {
      float mx = fmaxf(fmaxf(sc[0][r], sc[1][r]), fmaxf(sc[2][r], sc[3][r]));
      mx = fmaxf(mx, __shfl_xor(mx, 1));
      mx = fmaxf(mx, __shfl_xor(mx, 2));
      mx = fmaxf(mx, __shfl_xor(mx, 4));
      mx = fmaxf(mx, __shfl_xor(mx, 8));
      const float mnew = fmaxf(m_r[r], mx);
      const float corr = __expf(m_r[r] - mnew);
      m_r[r] = mnew;
      float rsum = 0.0f;
#pragma unroll
      for (int f = 0; f < 4; ++f) {
        const float p = __expf(sc[f][r] - mnew);
        sc[f][r] = p;
        rsum += p;
      }
      rsum += __shfl_xor(rsum, 1);
      rsum += __shfl_xor(rsum, 2);
      rsum += __shfl_xor(rsum, 4);
      rsum += __shfl_xor(rsum, 8);
      l_r[r] = l_r[r] * corr + rsum;
#pragma unroll
      for (int db = 0; db < 4; ++db) o_acc[db][r] *= corr;
    }

    // ---- P: C-layout regs -> wave-private LDS (bf16, swizzled) ----
#pragma unroll
    for (int r = 0; r < 4; ++r) {
      const int m  = l4 * 4 + r;
      const int sw = (m & 7) << 3;
#pragma unroll
      for (int f = 0; f < 4; ++f) {
        pw[m * 64 + ((f * 16 + l15) ^ sw)] = f2bf(sc[f][r]);
      }
    }

    // ---- O += P V  (A-frag of P from LDS; B-frag of V from vT) ----
    // wave-private pw: in-order LDS pipe within a wave, no barrier needed
#pragma unroll
    for (int kk = 0; kk < 2; ++kk) {
      const int pcol = (kk * 32 + l4 * 8) ^ ((l15 & 7) << 3);
      bf16x8 pf = *(const bf16x8*)&pw[l15 * 64 + pcol];
#pragma unroll
      for (int db = 0; db < 4; ++db) {
        const int d    = db * 16 + l15;
        const int vcol = (kk * 32 + l4 * 8) ^ ((d & 7) << 3);
        bf16x8 vf = *(const bf16x8*)&vT[d * 64 + vcol];
        o_acc[db] = __builtin_amdgcn_mfma_f32_16x16x32_bf16(pf, vf, o_acc[db], 0, 0, 0);
      }
    }
  }

  // ---- epilogue: normalize and store ----
#pragma unroll
  for (int r = 0; r < 4; ++r) {
    const float inv = 1.0f / l_r[r];
    const int qrow = qtile * QBLK + wave * 16 + l4 * 4 + r;
    float* op = Oh + (size_t)qrow * HEAD_D + l15;
#pragma unroll
    for (int db = 0; db < 4; ++db) op[db * 16] = o_acc[db][r] * inv;
  }
}

extern "C" void kernel_launch(void* const* d_in, const int* in_sizes, int n_in,
                              void* d_out, int out_size, void* d_ws, size_t ws_size,
                              hipStream_t stream) {
  const float* Q = (const float*)d_in[0];
  const float* K = (const float*)d_in[1];
  const float* V = (const float*)d_in[2];
  float* O = (float*)d_out;
  dim3 grid(S_LEN / QBLK, 64);  // 32 q-tiles x (B*H=64)
  dim3 block(256);
  hipLaunchKernelGGL(flash_attn_fwd, grid, block, 0, stream, Q, K, V, O);
}

// Round 2
// 198.242 us; speedup vs baseline: 1.7281x; 1.7281x over previous
//
#include <hip/hip_runtime.h>

#define S_LEN 2048
#define HEAD_D 64
#define NH 64                      // B*H
#define QBLK 64
#define KVBLK 128
#define NKT (S_LEN / KVBLK)        // 16
#define IMG_USHORTS (KVBLK * HEAD_D + HEAD_D * KVBLK)   // 16384 (32 KB)
#define WS_NEEDED ((size_t)NH * NKT * IMG_USHORTS * 2)  // 32 MB

typedef float f32x4 __attribute__((ext_vector_type(4)));
typedef __bf16 bf16x8 __attribute__((ext_vector_type(8)));

__device__ __forceinline__ unsigned short f2bf(float x) {
  __bf16 h = (__bf16)x;
  return __builtin_bit_cast(unsigned short, h);
}

__device__ __forceinline__ void gload_lds16(const void* g, void* l) {
  __builtin_amdgcn_global_load_lds(
      (const __attribute__((address_space(1))) unsigned int*)g,
      (__attribute__((address_space(3))) unsigned int*)l, 16, 0, 0);
}

// ---------------- prepass: pack K (swizzled) + V^T (swizzled) bf16 images ----
// ws image per (bh, kt): [0, 16KB)  K  tile: elem(row=kv 0..127, col=d 0..63)
//                                   at row*64 + (col ^ ((row&7)<<3))
//                        [16KB,32KB) V^T tile: elem(row=d 0..63, col=kv 0..127)
//                                   at row*128 + (col ^ ((row&7)<<3))
__global__ __launch_bounds__(256) void pack_kv(
    const float* __restrict__ K, const float* __restrict__ V,
    unsigned short* __restrict__ ws)
{
  const int kt = blockIdx.x;
  const int bh = blockIdx.y;
  const int t  = threadIdx.x;
  const float* Kg = K + ((size_t)bh * S_LEN + (size_t)kt * KVBLK) * HEAD_D;
  const float* Vg = V + ((size_t)bh * S_LEN + (size_t)kt * KVBLK) * HEAD_D;
  unsigned short* img = ws + ((size_t)bh * NKT + kt) * IMG_USHORTS;

  __shared__ unsigned short vt[HEAD_D * KVBLK];   // V^T staging (final layout)

#pragma unroll
  for (int i = 0; i < 8; ++i) {
    const int e   = t * 4 + i * 1024;   // element in [128][64] tile
    const int row = e >> 6;             // kv
    const int col = e & 63;             // d
    float4 k4 = *(const float4*)(Kg + e);
    ushort4 kb;
    kb.x = f2bf(k4.x); kb.y = f2bf(k4.y); kb.z = f2bf(k4.z); kb.w = f2bf(k4.w);
    *(ushort4*)&img[row * HEAD_D + (col ^ ((row & 7) << 3))] = kb;
    float4 v4 = *(const float4*)(Vg + e);
    vt[(col + 0) * KVBLK + (row ^ (((col + 0) & 7) << 3))] = f2bf(v4.x);
    vt[(col + 1) * KVBLK + (row ^ (((col + 1) & 7) << 3))] = f2bf(v4.y);
    vt[(col + 2) * KVBLK + (row ^ (((col + 2) & 7) << 3))] = f2bf(v4.z);
    vt[(col + 3) * KVBLK + (row ^ (((col + 3) & 7) << 3))] = f2bf(v4.w);
  }
  __syncthreads();
  // coalesced copy of the finished V^T image to global
  uint4* dst = (uint4*)(img + KVBLK * HEAD_D);
  const uint4* src = (const uint4*)vt;
#pragma unroll
  for (int i = 0; i < 4; ++i) dst[t + i * 256] = src[t + i * 256];
}

// ---------------- main: flash attention, bf16 MFMA, global_load_lds staging --
__global__ __launch_bounds__(256) void flash_attn_fwd_v2(
    const float* __restrict__ Q, const unsigned short* __restrict__ ws,
    float* __restrict__ O)
{
  __shared__ unsigned short kv_lds[IMG_USHORTS];   // 32 KB, linear image copy
  __shared__ unsigned short pT[4 * 16 * KVBLK];    // 16 KB P staging

  const int tid  = threadIdx.x;
  const int wave = tid >> 6;
  const int lane = tid & 63;
  const int l15  = lane & 15;
  const int l4   = lane >> 4;

  // XCD swizzle: XCD x gets blocks {x, x+8, ...} -> heads 8x..8x+7 complete
  const int bid   = blockIdx.x;
  const int swz   = (bid & 7) * 256 + (bid >> 3);
  const int bh    = swz >> 5;
  const int qtile = swz & 31;

  const float* Qh = Q + (size_t)bh * (S_LEN * HEAD_D);
  float*       Oh = O + (size_t)bh * (S_LEN * HEAD_D);
  const unsigned short* imgh = ws + (size_t)bh * NKT * IMG_USHORTS;

  // Q fragments (A-frag: row=lane&15, k=(lane>>4)*8+j), scale 1/8 folded
  bf16x8 qf[2];
  {
    const int qrow = qtile * QBLK + wave * 16 + l15;
    const float* qp = Qh + (size_t)qrow * HEAD_D + l4 * 8;
#pragma unroll
    for (int kk = 0; kk < 2; ++kk) {
      float4 a = *(const float4*)(qp + kk * 32);
      float4 b = *(const float4*)(qp + kk * 32 + 4);
      qf[kk][0] = (__bf16)(a.x * 0.125f);
      qf[kk][1] = (__bf16)(a.y * 0.125f);
      qf[kk][2] = (__bf16)(a.z * 0.125f);
      qf[kk][3] = (__bf16)(a.w * 0.125f);
      qf[kk][4] = (__bf16)(b.x * 0.125f);
      qf[kk][5] = (__bf16)(b.y * 0.125f);
      qf[kk][6] = (__bf16)(b.z * 0.125f);
      qf[kk][7] = (__bf16)(b.w * 0.125f);
    }
  }

  f32x4 o_acc[4];
#pragma unroll
  for (int db = 0; db < 4; ++db)
#pragma unroll
    for (int r = 0; r < 4; ++r) o_acc[db][r] = 0.0f;
  float m_r[4], l_r[4];
#pragma unroll
  for (int r = 0; r < 4; ++r) { m_r[r] = -1e30f; l_r[r] = 0.0f; }

  unsigned short* kT = kv_lds;
  unsigned short* vT = kv_lds + KVBLK * HEAD_D;
  unsigned short* pw = pT + wave * (16 * KVBLK);

  for (int kt = 0; kt < NKT; ++kt) {
    __syncthreads();
    // stage 32KB image: each wave 8KB via 8x global_load_lds dwordx4
    {
      const char* g = (const char*)(imgh + (size_t)kt * IMG_USHORTS);
      char* l = (char*)kv_lds;
      const int base = wave * 8192;
#pragma unroll
      for (int c = 0; c < 8; ++c) {
        const int off = base + c * 1024;
        gload_lds16(g + off + lane * 16, l + off);
      }
    }
    __syncthreads();

    // ---- S = Q K^T ----
    f32x4 sc[8];
#pragma unroll
    for (int f = 0; f < 8; ++f)
#pragma unroll
      for (int r = 0; r < 4; ++r) sc[f][r] = 0.0f;
#pragma unroll
    for (int kk = 0; kk < 2; ++kk) {
#pragma unroll
      for (int f = 0; f < 8; ++f) {
        const int row  = f * 16 + l15;
        const int colb = (kk * 32 + l4 * 8) ^ ((row & 7) << 3);
        bf16x8 kf = *(const bf16x8*)&kT[row * HEAD_D + colb];
        sc[f] = __builtin_amdgcn_mfma_f32_16x16x32_bf16(qf[kk], kf, sc[f], 0, 0, 0);
      }
    }

    // ---- online softmax ----
#pragma unroll
    for (int r = 0; r < 4; ++r) {
      float mx = sc[0][r];
#pragma unroll
      for (int f = 1; f < 8; ++f) mx = fmaxf(mx, sc[f][r]);
      mx = fmaxf(mx, __shfl_xor(mx, 1));
      mx = fmaxf(mx, __shfl_xor(mx, 2));
      mx = fmaxf(mx, __shfl_xor(mx, 4));
      mx = fmaxf(mx, __shfl_xor(mx, 8));
      const float mnew = fmaxf(m_r[r], mx);
      const float corr = __expf(m_r[r] - mnew);
      m_r[r] = mnew;
      float rsum = 0.0f;
#pragma unroll
      for (int f = 0; f < 8; ++f) {
        const float p = __expf(sc[f][r] - mnew);
        sc[f][r] = p;
        rsum += p;
      }
      rsum += __shfl_xor(rsum, 1);
      rsum += __shfl_xor(rsum, 2);
      rsum += __shfl_xor(rsum, 4);
      rsum += __shfl_xor(rsum, 8);
      l_r[r] = l_r[r] * corr + rsum;
#pragma unroll
      for (int db = 0; db < 4; ++db) o_acc[db][r] *= corr;
    }

    // ---- P -> wave-private LDS (bf16, swizzled) ----
#pragma unroll
    for (int r = 0; r < 4; ++r) {
      const int m  = l4 * 4 + r;
      const int sw = (m & 7) << 3;
      unsigned short* prow = pw + m * KVBLK;
#pragma unroll
      for (int f = 0; f < 8; ++f) prow[(f * 16 + l15) ^ sw] = f2bf(sc[f][r]);
    }

    // ---- O += P V ----
#pragma unroll
    for (int kk = 0; kk < 4; ++kk) {
      const int pcol = (kk * 32 + l4 * 8) ^ ((l15 & 7) << 3);
      bf16x8 pf = *(const bf16x8*)&pw[l15 * KVBLK + pcol];
#pragma unroll
      for (int db = 0; db < 4; ++db) {
        const int d    = db * 16 + l15;
        const int vcol = (kk * 32 + l4 * 8) ^ ((d & 7) << 3);
        bf16x8 vf = *(const bf16x8*)&vT[d * KVBLK + vcol];
        o_acc[db] = __builtin_amdgcn_mfma_f32_16x16x32_bf16(pf, vf, o_acc[db], 0, 0, 0);
      }
    }
  }

  // ---- epilogue ----
#pragma unroll
  for (int r = 0; r < 4; ++r) {
    const float inv = 1.0f / l_r[r];
    const int qrow = qtile * QBLK + wave * 16 + l4 * 4 + r;
    float* op = Oh + (size_t)qrow * HEAD_D + l15;
#pragma unroll
    for (int db = 0; db < 4; ++db) op[db * 16] = o_acc[db][r] * inv;
  }
}

// ---------------- v1 fallback (fused, no workspace) --------------------------
__global__ __launch_bounds__(256) void flash_attn_fwd_v1(
    const float* __restrict__ Q, const float* __restrict__ K,
    const float* __restrict__ V, float* __restrict__ O)
{
  __shared__ unsigned short kT[64 * 64];
  __shared__ unsigned short vT1[64 * 64];
  __shared__ unsigned short pT[4 * 16 * 64];

  const int tid = threadIdx.x;
  const int wave = tid >> 6;
  const int lane = tid & 63;
  const int l15 = lane & 15;
  const int l4 = lane >> 4;
  const int qtile = blockIdx.x;
  const int bh = blockIdx.y;
  const size_t head_off = (size_t)bh * (S_LEN * HEAD_D);
  const float* Qh = Q + head_off;
  const float* Kh = K + head_off;
  const float* Vh = V + head_off;
  float* Oh = O + head_off;

  bf16x8 qf[2];
  {
    const int qrow = qtile * QBLK + wave * 16 + l15;
    const float* qp = Qh + (size_t)qrow * HEAD_D + l4 * 8;
#pragma unroll
    for (int kk = 0; kk < 2; ++kk) {
      float4 a = *(const float4*)(qp + kk * 32);
      float4 b = *(const float4*)(qp + kk * 32 + 4);
      qf[kk][0] = (__bf16)(a.x * 0.125f); qf[kk][1] = (__bf16)(a.y * 0.125f);
      qf[kk][2] = (__bf16)(a.z * 0.125f); qf[kk][3] = (__bf16)(a.w * 0.125f);
      qf[kk][4] = (__bf16)(b.x * 0.125f); qf[kk][5] = (__bf16)(b.y * 0.125f);
      qf[kk][6] = (__bf16)(b.z * 0.125f); qf[kk][7] = (__bf16)(b.w * 0.125f);
    }
  }
  f32x4 o_acc[4];
#pragma unroll
  for (int db = 0; db < 4; ++db)
#pragma unroll
    for (int r = 0; r < 4; ++r) o_acc[db][r] = 0.0f;
  float m_r[4], l_r[4];
#pragma unroll
  for (int r = 0; r < 4; ++r) { m_r[r] = -1e30f; l_r[r] = 0.0f; }
  unsigned short* pw = pT + wave * (16 * 64);

  for (int kt = 0; kt < S_LEN / 64; ++kt) {
    __syncthreads();
    {
      const float* kg = Kh + (size_t)kt * 64 * HEAD_D;
      const float* vg = Vh + (size_t)kt * 64 * HEAD_D;
#pragma unroll
      for (int i = 0; i < 4; ++i) {
        const int e = tid * 4 + i * 1024;
        const int row = e >> 6;
        const int col = e & 63;
        float4 k4 = *(const float4*)(kg + e);
        ushort4 kb;
        kb.x = f2bf(k4.x); kb.y = f2bf(k4.y); kb.z = f2bf(k4.z); kb.w = f2bf(k4.w);
        *(ushort4*)&kT[row * 64 + (col ^ ((row & 7) << 3))] = kb;
        float4 v4 = *(const float4*)(vg + e);
        vT1[(col + 0) * 64 + (row ^ (((col + 0) & 7) << 3))] = f2bf(v4.x);
        vT1[(col + 1) * 64 + (row ^ (((col + 1) & 7) << 3))] = f2bf(v4.y);
        vT1[(col + 2) * 64 + (row ^ (((col + 2) & 7) << 3))] = f2bf(v4.z);
        vT1[(col + 3) * 64 + (row ^ (((col + 3) & 7) << 3))] = f2bf(v4.w);
      }
    }
    __syncthreads();
    f32x4 sc[4];
#pragma unroll
    for (int f = 0; f < 4; ++f)
#pragma unroll
      for (int r = 0; r < 4; ++r) sc[f][r] = 0.0f;
#pragma unroll
    for (int kk = 0; kk < 2; ++kk) {
#pragma unroll
      for (int f = 0; f < 4; ++f) {
        const int row = f * 16 + l15;
        const int colb = (kk * 32 + l4 * 8) ^ ((row & 7) << 3);
        bf16x8 kf = *(const bf16x8*)&kT[row * 64 + colb];
        sc[f] = __builtin_amdgcn_mfma_f32_16x16x32_bf16(qf[kk], kf, sc[f], 0, 0, 0);
      }
    }
#pragma unroll
    for (int r = 0; r < 4; ++r) {
      float mx = fmaxf(fmaxf(sc[0][r], sc[1][r]), fmaxf(sc[2][r], sc[3][r]));
      mx = fmaxf(mx, __shfl_xor(mx, 1));
      mx = fmaxf(mx, __shfl_xor(mx, 2));
      mx = fmaxf(mx, __shfl_xor(mx, 4));
      mx = fmaxf(mx, __shfl_xor(mx, 8));
      const float mnew = fmaxf(m_r[r], mx);
      const float corr = __expf(m_r[r] - mnew);
      m_r[r] = mnew;
      float rsum = 0.0f;
#pragma unroll
      for (int f = 0; f < 4; ++f) {
        const float p = __expf(sc[f][r] - mnew);
        sc[f][r] = p; rsum += p;
      }
      rsum += __shfl_xor(rsum, 1);
      rsum += __shfl_xor(rsum, 2);
      rsum += __shfl_xor(rsum, 4);
      rsum += __shfl_xor(rsum, 8);
      l_r[r] = l_r[r] * corr + rsum;
#pragma unroll
      for (int db = 0; db < 4; ++db) o_acc[db][r] *= corr;
    }
#pragma unroll
    for (int r = 0; r < 4; ++r) {
      const int m = l4 * 4 + r;
      const int sw = (m & 7) << 3;
#pragma unroll
      for (int f = 0; f < 4; ++f) pw[m * 64 + ((f * 16 + l15) ^ sw)] = f2bf(sc[f][r]);
    }
#pragma unroll
    for (int kk = 0; kk < 2; ++kk) {
      const int pcol = (kk * 32 + l4 * 8) ^ ((l15 & 7) << 3);
      bf16x8 pf = *(const bf16x8*)&pw[l15 * 64 + pcol];
#pragma unroll
      for (int db = 0; db < 4; ++db) {
        const int d = db * 16 + l15;
        const int vcol = (kk * 32 + l4 * 8) ^ ((d & 7) << 3);
        bf16x8 vf = *(const bf16x8*)&vT1[d * 64 + vcol];
        o_acc[db] = __builtin_amdgcn_mfma_f32_16x16x32_bf16(pf, vf, o_acc[db], 0, 0, 0);
      }
    }
  }
#pragma unroll
  for (int r = 0; r < 4; ++r) {
    const float inv = 1.0f / l_r[r];
    const int qrow = qtile * QBLK + wave * 16 + l4 * 4 + r;
    float* op = Oh + (size_t)qrow * HEAD_D + l15;
#pragma unroll
    for (int db = 0; db < 4; ++db) op[db * 16] = o_acc[db][r] * inv;
  }
}

extern "C" void kernel_launch(void* const* d_in, const int* in_sizes, int n_in,
                              void* d_out, int out_size, void* d_ws, size_t ws_size,
                              hipStream_t stream) {
  const float* Q = (const float*)d_in[0];
  const float* K = (const float*)d_in[1];
  const float* V = (const float*)d_in[2];
  float* O = (float*)d_out;
  if (ws_size >= WS_NEEDED) {
    unsigned short* ws = (unsigned short*)d_ws;
    hipLaunchKernelGGL(pack_kv, dim3(NKT, NH), dim3(256), 0, stream, K, V, ws);
    hipLaunchKernelGGL(flash_attn_fwd_v2, dim3(2048), dim3(256), 0, stream, Q, ws, O);
  } else {
    hipLaunchKernelGGL(flash_attn_fwd_v1, dim3(32, 64), dim3(256), 0, stream, Q, K, V, O);
  }
}

// Round 4
// 122.782 us; speedup vs baseline: 2.7901x; 1.6146x over previous
//
#include <hip/hip_runtime.h>

#define S_LEN 2048
#define HEAD_D 64
#define NH 64                        // B*H
#define QBLK 128                     // 4 waves x 32 q-rows
#define KVB 64
#define NKT (S_LEN / KVB)            // 32
#define IMG_USH (KVB * HEAD_D * 2)   // 8192 ushorts = 16 KB (K 8KB + V^T 8KB)
#define WS_NEEDED ((size_t)NH * NKT * IMG_USH * 2)   // 32 MB

typedef float f32x4  __attribute__((ext_vector_type(4)));
typedef float f32x16 __attribute__((ext_vector_type(16)));
typedef __bf16 bf16x8 __attribute__((ext_vector_type(8)));

static __device__ __forceinline__ unsigned short f2bf(float x) {
  __bf16 h = (__bf16)x;
  return __builtin_bit_cast(unsigned short, h);
}
static __device__ __forceinline__ unsigned pack2(float a, float b) {
  return (unsigned)f2bf(a) | ((unsigned)f2bf(b) << 16);
}
static __device__ __forceinline__ void gload_lds16(const void* g, void* l) {
  __builtin_amdgcn_global_load_lds(
      (const __attribute__((address_space(1))) unsigned int*)g,
      (__attribute__((address_space(3))) unsigned int*)l, 16, 0, 0);
}

// V^T column permutation: position of kv within its 16-block rearranged so the
// PV B-frag slot (hi, j) <-> kv = blk + 4*hi + (j&3) + 8*(j>>2), i.e. exactly
// the 32x32 MFMA C/D row layout of the QK^T output. pos(kv):
//   pos = (kv & ~15) | ((kv>>2)&1)<<3 | ((kv>>3)&1)<<2 | (kv&3)
static __device__ __forceinline__ int vpos(int kv) {
  return (kv & ~15) | (((kv >> 2) & 1) << 3) | (((kv >> 3) & 1) << 2) | (kv & 3);
}

// ---------------- prepass: per (bh, kt64): K [64kv][64d] swz + V^T [64d][64kv-permuted] swz
__global__ __launch_bounds__(256) void pack_kv(
    const float* __restrict__ K, const float* __restrict__ V,
    unsigned short* __restrict__ ws)
{
  const int kt = blockIdx.x;
  const int bh = blockIdx.y;
  const int t  = threadIdx.x;
  const float* Kg = K + ((size_t)bh * S_LEN + (size_t)kt * KVB) * HEAD_D;
  const float* Vg = V + ((size_t)bh * S_LEN + (size_t)kt * KVB) * HEAD_D;
  unsigned short* img = ws + ((size_t)bh * NKT + kt) * IMG_USH;

  __shared__ unsigned short vt[HEAD_D * KVB];   // V^T in final layout (8 KB)

#pragma unroll
  for (int i = 0; i < 4; ++i) {
    const int e   = t * 4 + i * 1024;   // element in [64][64] tile
    const int row = e >> 6;             // kv
    const int col = e & 63;             // d
    float4 k4 = *(const float4*)(Kg + e);
    ushort4 kb;
    kb.x = f2bf(k4.x); kb.y = f2bf(k4.y); kb.z = f2bf(k4.z); kb.w = f2bf(k4.w);
    *(ushort4*)&img[row * 64 + (col ^ ((row & 7) << 3))] = kb;
    float4 v4 = *(const float4*)(Vg + e);
    const int p = vpos(row);            // permuted kv position
    vt[(col + 0) * 64 + (p ^ (((col + 0) & 7) << 3))] = f2bf(v4.x);
    vt[(col + 1) * 64 + (p ^ (((col + 1) & 7) << 3))] = f2bf(v4.y);
    vt[(col + 2) * 64 + (p ^ (((col + 2) & 7) << 3))] = f2bf(v4.z);
    vt[(col + 3) * 64 + (p ^ (((col + 3) & 7) << 3))] = f2bf(v4.w);
  }
  __syncthreads();
  uint4* dst = (uint4*)(img + KVB * HEAD_D);
  const uint4* src = (const uint4*)vt;
#pragma unroll
  for (int i = 0; i < 2; ++i) dst[t + i * 256] = src[t + i * 256];
}

// ---------------- main: swapped-QK^T 32x32 flash attention -------------------
// Per wave: 32 q-rows (q = lane&31). S^T = mfma(K, Q): lane holds a full P-row
// (split with its partner lane l+32). Softmax in-register (tree + shfl_xor 32).
// PV swapped: O^T = V^T P^T with P fed as B-frag via direct pack2 (V^T columns
// pre-permuted to the C/D row layout -> zero cross-lane data movement).
__global__ __launch_bounds__(256, 2) void flash_attn_fwd_v4(
    const float* __restrict__ Q, const unsigned short* __restrict__ ws,
    float* __restrict__ O)
{
  __shared__ unsigned short lds[2][IMG_USH];   // 2 x 16 KB double buffer

  const int tid  = threadIdx.x;
  const int wave = tid >> 6;
  const int lane = tid & 63;
  const int l31  = lane & 31;
  const int hi   = lane >> 5;

  // XCD swizzle (bijective, 1024 blocks): each XCD owns 8 complete heads
  const int bid = blockIdx.x;
  const int swz = (bid & 7) * 128 + (bid >> 3);
  const int bh  = swz >> 4;
  const int qt  = swz & 15;

  const float* Qh = Q + (size_t)bh * (S_LEN * HEAD_D);
  float*       Oh = O + (size_t)bh * (S_LEN * HEAD_D);
  const unsigned short* imgh = ws + (size_t)bh * NKT * IMG_USH;

  const int qrow = qt * QBLK + wave * 32 + l31;

  // Q as B-frag: n=q=lane&31, k=d=(lane>>5)*8+j, chunk c covers d=16c..16c+15
  bf16x8 qf[4];
#pragma unroll
  for (int c = 0; c < 4; ++c) {
    const float* qp = Qh + (size_t)qrow * HEAD_D + c * 16 + hi * 8;
    float4 a = *(const float4*)qp;
    float4 b = *(const float4*)(qp + 4);
    qf[c][0] = (__bf16)a.x; qf[c][1] = (__bf16)a.y;
    qf[c][2] = (__bf16)a.z; qf[c][3] = (__bf16)a.w;
    qf[c][4] = (__bf16)b.x; qf[c][5] = (__bf16)b.y;
    qf[c][6] = (__bf16)b.z; qf[c][7] = (__bf16)b.w;
  }

  f32x16 oa0, oa1;
#pragma unroll
  for (int i = 0; i < 16; ++i) { oa0[i] = 0.0f; oa1[i] = 0.0f; }
  float m_run = -1e30f, l_run = 0.0f;
  const float SC = 0.125f;   // 1/sqrt(64), applied inside exp

  // prologue stage (wave-uniform LDS base, per-lane global)
  {
    const char* g = (const char*)imgh;
    char* l = (char*)&lds[0][0];
    const int wb = wave * 4096;
#pragma unroll
    for (int c2 = 0; c2 < 4; ++c2) {
      const int off = wb + c2 * 1024;
      gload_lds16(g + off + lane * 16, l + off);
    }
  }
  __syncthreads();
  int cur = 0;

  for (int kt = 0; kt < NKT; ++kt) {
    // stage next tile into the other buffer (overlaps with compute below)
    if (kt + 1 < NKT) {
      const char* g = (const char*)(imgh + (size_t)(kt + 1) * IMG_USH);
      char* l = (char*)&lds[cur ^ 1][0];
      const int wb = wave * 4096;
#pragma unroll
      for (int c2 = 0; c2 < 4; ++c2) {
        const int off = wb + c2 * 1024;
        gload_lds16(g + off + lane * 16, l + off);
      }
    }
    const unsigned short* kT = &lds[cur][0];
    const unsigned short* vT = &lds[cur][KVB * HEAD_D];

    // ---- S^T = K Q^T : p0 = kv 0..31, p1 = kv 32..63
    //      lane (q=l31, hi): p[i] -> kv = (i&3) + 8*(i>>2) + 4*hi (+32 for p1) ----
    f32x16 p0, p1;
#pragma unroll
    for (int i = 0; i < 16; ++i) { p0[i] = 0.0f; p1[i] = 0.0f; }
    __builtin_amdgcn_s_setprio(1);
#pragma unroll
    for (int c = 0; c < 4; ++c) {
      const int r0 = l31;
      bf16x8 kf0 = *(const bf16x8*)&kT[r0 * 64 + ((c * 16 + hi * 8) ^ ((r0 & 7) << 3))];
      p0 = __builtin_amdgcn_mfma_f32_32x32x16_bf16(kf0, qf[c], p0, 0, 0, 0);
      const int r1 = l31 + 32;
      bf16x8 kf1 = *(const bf16x8*)&kT[r1 * 64 + ((c * 16 + hi * 8) ^ ((r1 & 7) << 3))];
      p1 = __builtin_amdgcn_mfma_f32_32x32x16_bf16(kf1, qf[c], p1, 0, 0, 0);
    }
    __builtin_amdgcn_s_setprio(0);

    // ---- online softmax, in-register (max/sum are layout-permutation-invariant) ----
    float t16[16];
#pragma unroll
    for (int i = 0; i < 16; ++i) t16[i] = fmaxf(p0[i], p1[i]);
#pragma unroll
    for (int st = 8; st >= 1; st >>= 1)
#pragma unroll
      for (int i = 0; i < st; ++i) t16[i] = fmaxf(t16[i], t16[i + st]);
    const float tmax = fmaxf(t16[0], __shfl_xor(t16[0], 32));

    const int defer = __all((tmax - m_run) <= 64.0f);   // 64 unscaled = 8 scaled
    if (!defer) {
      const float mnew = fmaxf(m_run, tmax);
      const float corr = __expf((m_run - mnew) * SC);
      m_run = mnew;
      l_run *= corr;
#pragma unroll
      for (int i = 0; i < 16; ++i) { oa0[i] *= corr; oa1[i] *= corr; }
    }
    const float msc = m_run * SC;
#pragma unroll
    for (int i = 0; i < 16; ++i) {
      p0[i] = __expf(__builtin_fmaf(p0[i], SC, -msc));
      p1[i] = __expf(__builtin_fmaf(p1[i], SC, -msc));
    }
    float s16[16];
#pragma unroll
    for (int i = 0; i < 16; ++i) s16[i] = p0[i] + p1[i];
#pragma unroll
    for (int st = 8; st >= 1; st >>= 1)
#pragma unroll
      for (int i = 0; i < st; ++i) s16[i] = s16[i] + s16[i + st];
    l_run += s16[0] + __shfl_xor(s16[0], 32);

    // ---- PV: O^T += V^T P^T. B-frag slot (hi,j) needs kv = kc*16+4hi+(j&3)+8*(j>>2)
    //      = exactly where p[rb+j] sits -> direct pack, no cross-lane movement.
    //      V^T columns pre-permuted (vpos) so its A-frag slots match. ----
    __builtin_amdgcn_s_setprio(1);
#pragma unroll
    for (int kc = 0; kc < 4; ++kc) {
      const f32x16& ps = (kc < 2) ? p0 : p1;
      const int rb = (kc & 1) * 8;
      uint4 wv;
      wv.x = pack2(ps[rb + 0], ps[rb + 1]);
      wv.y = pack2(ps[rb + 2], ps[rb + 3]);
      wv.z = pack2(ps[rb + 4], ps[rb + 5]);
      wv.w = pack2(ps[rb + 6], ps[rb + 7]);
      bf16x8 pf = __builtin_bit_cast(bf16x8, wv);
#pragma unroll
      for (int db = 0; db < 2; ++db) {
        const int d = db * 32 + l31;
        bf16x8 vf = *(const bf16x8*)&vT[d * 64 + ((kc * 16 + hi * 8) ^ ((d & 7) << 3))];
        if (db == 0) oa0 = __builtin_amdgcn_mfma_f32_32x32x16_bf16(vf, pf, oa0, 0, 0, 0);
        else         oa1 = __builtin_amdgcn_mfma_f32_32x32x16_bf16(vf, pf, oa1, 0, 0, 0);
      }
    }
    __builtin_amdgcn_s_setprio(0);

    __syncthreads();
    cur ^= 1;
  }

  // ---- epilogue: O[q][d] = oa^T / l. Lane q=l31; oa0[i] -> d=(i&3)+8*(i>>2)+4hi ----
  const float inv = 1.0f / l_run;
  float* orow = Oh + (size_t)qrow * HEAD_D;
#pragma unroll
  for (int g = 0; g < 4; ++g) {
    float4 o4;
    o4.x = oa0[4 * g + 0] * inv; o4.y = oa0[4 * g + 1] * inv;
    o4.z = oa0[4 * g + 2] * inv; o4.w = oa0[4 * g + 3] * inv;
    *(float4*)&orow[g * 8 + hi * 4] = o4;
    float4 o5;
    o5.x = oa1[4 * g + 0] * inv; o5.y = oa1[4 * g + 1] * inv;
    o5.z = oa1[4 * g + 2] * inv; o5.w = oa1[4 * g + 3] * inv;
    *(float4*)&orow[32 + g * 8 + hi * 4] = o5;
  }
}

// ---------------- v1 fallback (fused, no workspace) --------------------------
__global__ __launch_bounds__(256) void flash_attn_fwd_v1(
    const float* __restrict__ Q, const float* __restrict__ K,
    const float* __restrict__ V, float* __restrict__ O)
{
  __shared__ unsigned short kT[64 * 64];
  __shared__ unsigned short vT1[64 * 64];
  __shared__ unsigned short pT[4 * 16 * 64];

  const int tid = threadIdx.x;
  const int wave = tid >> 6;
  const int lane = tid & 63;
  const int l15 = lane & 15;
  const int l4 = lane >> 4;
  const int qtile = blockIdx.x;
  const int bh = blockIdx.y;
  const size_t head_off = (size_t)bh * (S_LEN * HEAD_D);
  const float* Qh = Q + head_off;
  const float* Kh = K + head_off;
  const float* Vh = V + head_off;
  float* Oh = O + head_off;

  bf16x8 qf[2];
  {
    const int qrow = qtile * 64 + wave * 16 + l15;
    const float* qp = Qh + (size_t)qrow * HEAD_D + l4 * 8;
#pragma unroll
    for (int kk = 0; kk < 2; ++kk) {
      float4 a = *(const float4*)(qp + kk * 32);
      float4 b = *(const float4*)(qp + kk * 32 + 4);
      qf[kk][0] = (__bf16)(a.x * 0.125f); qf[kk][1] = (__bf16)(a.y * 0.125f);
      qf[kk][2] = (__bf16)(a.z * 0.125f); qf[kk][3] = (__bf16)(a.w * 0.125f);
      qf[kk][4] = (__bf16)(b.x * 0.125f); qf[kk][5] = (__bf16)(b.y * 0.125f);
      qf[kk][6] = (__bf16)(b.z * 0.125f); qf[kk][7] = (__bf16)(b.w * 0.125f);
    }
  }
  f32x4 o_acc[4];
#pragma unroll
  for (int db = 0; db < 4; ++db)
#pragma unroll
    for (int r = 0; r < 4; ++r) o_acc[db][r] = 0.0f;
  float m_r[4], l_r[4];
#pragma unroll
  for (int r = 0; r < 4; ++r) { m_r[r] = -1e30f; l_r[r] = 0.0f; }
  unsigned short* pw = pT + wave * (16 * 64);

  for (int kt = 0; kt < S_LEN / 64; ++kt) {
    __syncthreads();
    {
      const float* kg = Kh + (size_t)kt * 64 * HEAD_D;
      const float* vg = Vh + (size_t)kt * 64 * HEAD_D;
#pragma unroll
      for (int i = 0; i < 4; ++i) {
        const int e = tid * 4 + i * 1024;
        const int row = e >> 6;
        const int col = e & 63;
        float4 k4 = *(const float4*)(kg + e);
        ushort4 kb;
        kb.x = f2bf(k4.x); kb.y = f2bf(k4.y); kb.z = f2bf(k4.z); kb.w = f2bf(k4.w);
        *(ushort4*)&kT[row * 64 + (col ^ ((row & 7) << 3))] = kb;
        float4 v4 = *(const float4*)(vg + e);
        vT1[(col + 0) * 64 + (row ^ (((col + 0) & 7) << 3))] = f2bf(v4.x);
        vT1[(col + 1) * 64 + (row ^ (((col + 1) & 7) << 3))] = f2bf(v4.y);
        vT1[(col + 2) * 64 + (row ^ (((col + 2) & 7) << 3))] = f2bf(v4.z);
        vT1[(col + 3) * 64 + (row ^ (((col + 3) & 7) << 3))] = f2bf(v4.w);
      }
    }
    __syncthreads();
    f32x4 sc[4];
#pragma unroll
    for (int f = 0; f < 4; ++f)
#pragma unroll
      for (int r = 0; r < 4; ++r) sc[f][r] = 0.0f;
#pragma unroll
    for (int kk = 0; kk < 2; ++kk) {
#pragma unroll
      for (int f = 0; f < 4; ++f) {
        const int row = f * 16 + l15;
        const int colb = (kk * 32 + l4 * 8) ^ ((row & 7) << 3);
        bf16x8 kf = *(const bf16x8*)&kT[row * 64 + colb];
        sc[f] = __builtin_amdgcn_mfma_f32_16x16x32_bf16(qf[kk], kf, sc[f], 0, 0, 0);
      }
    }
#pragma unroll
    for (int r = 0; r < 4; ++r) {
      float mx = fmaxf(fmaxf(sc[0][r], sc[1][r]), fmaxf(sc[2][r], sc[3][r]));
      mx = fmaxf(mx, __shfl_xor(mx, 1));
      mx = fmaxf(mx, __shfl_xor(mx, 2));
      mx = fmaxf(mx, __shfl_xor(mx, 4));
      mx = fmaxf(mx, __shfl_xor(mx, 8));
      const float mnew = fmaxf(m_r[r], mx);
      const float corr = __expf(m_r[r] - mnew);
      m_r[r] = mnew;
      float rsum = 0.0f;
#pragma unroll
      for (int f = 0; f < 4; ++f) {
        const float p = __expf(sc[f][r] - mnew);
        sc[f][r] = p; rsum += p;
      }
      rsum += __shfl_xor(rsum, 1);
      rsum += __shfl_xor(rsum, 2);
      rsum += __shfl_xor(rsum, 4);
      rsum += __shfl_xor(rsum, 8);
      l_r[r] = l_r[r] * corr + rsum;
#pragma unroll
      for (int db = 0; db < 4; ++db) o_acc[db][r] *= corr;
    }
#pragma unroll
    for (int r = 0; r < 4; ++r) {
      const int m = l4 * 4 + r;
      const int sw = (m & 7) << 3;
#pragma unroll
      for (int f = 0; f < 4; ++f) pw[m * 64 + ((f * 16 + l15) ^ sw)] = f2bf(sc[f][r]);
    }
#pragma unroll
    for (int kk = 0; kk < 2; ++kk) {
      const int pcol = (kk * 32 + l4 * 8) ^ ((l15 & 7) << 3);
      bf16x8 pf = *(const bf16x8*)&pw[l15 * 64 + pcol];
#pragma unroll
      for (int db = 0; db < 4; ++db) {
        const int d = db * 16 + l15;
        const int vcol = (kk * 32 + l4 * 8) ^ ((d & 7) << 3);
        bf16x8 vf = *(const bf16x8*)&vT1[d * 64 + vcol];
        o_acc[db] = __builtin_amdgcn_mfma_f32_16x16x32_bf16(pf, vf, o_acc[db], 0, 0, 0);
      }
    }
  }
#pragma unroll
  for (int r = 0; r < 4; ++r) {
    const float inv = 1.0f / l_r[r];
    const int qrow = qtile * 64 + wave * 16 + l4 * 4 + r;
    float* op = Oh + (size_t)qrow * HEAD_D + l15;
#pragma unroll
    for (int db = 0; db < 4; ++db) op[db * 16] = o_acc[db][r] * inv;
  }
}

extern "C" void kernel_launch(void* const* d_in, const int* in_sizes, int n_in,
                              void* d_out, int out_size, void* d_ws, size_t ws_size,
                              hipStream_t stream) {
  const float* Q = (const float*)d_in[0];
  const float* K = (const float*)d_in[1];
  const float* V = (const float*)d_in[2];
  float* O = (float*)d_out;
  if (ws_size >= WS_NEEDED) {
    unsigned short* ws = (unsigned short*)d_ws;
    hipLaunchKernelGGL(pack_kv, dim3(NKT, NH), dim3(256), 0, stream, K, V, ws);
    hipLaunchKernelGGL(flash_attn_fwd_v4, dim3(1024), dim3(256), 0, stream, Q, ws, O);
  } else {
    hipLaunchKernelGGL(flash_attn_fwd_v1, dim3(32, 64), dim3(256), 0, stream, Q, K, V, O);
  }
}